// Round 1
// 200.233 us; speedup vs baseline: 1.0564x; 1.0564x over previous
//
#include <hip/hip_runtime.h>
#include <hip/hip_bf16.h>

// HaloNet-style windowed attention, MI355X gfx950.  f32 in / f32 out.
// bf16 MFMA internals; w hi/lo split keeps conv weights exact; x/q/k/v/P/ao
// single bf16 (absmax ~4.9e-4 vs 2.54e-3 threshold).
// ws layout (shorts):
//   q_t [head][pix][16]                    12,582,912   (scaled 0.25*log2e)
//   k_t [head*2+b][260*260 padded][16]     12,979,200   (2-px ZERO border)
//   v_t [head][pix][16]                    12,582,912
//   ao  [head][pix][16]                    12,582,912   (head-major: full-line writes)
//   weights/tables                              74,464
// Total ~101.6 MB.

typedef __attribute__((ext_vector_type(8))) short bf16x8;
typedef __attribute__((ext_vector_type(4))) float f32x4;

__device__ __forceinline__ f32x4 mfma16(bf16x8 a, bf16x8 b, f32x4 c) {
  // C/D: col=lane&15 (B-idx), row=(lane>>4)*4+reg (A-idx)
  // A/B frag: idx=lane&15, k=(lane>>4)*8+j   [learn_hip m89/m91]
  return __builtin_amdgcn_mfma_f32_16x16x32_bf16(a, b, c, 0, 0, 0);
}
// branchless RNE f32->bf16 (finite inputs only — true for this problem)
__device__ __forceinline__ short f2b(float f) {
  unsigned u = __builtin_bit_cast(unsigned, f);
  unsigned r = u + 0x7fffu + ((u >> 16) & 1u);
  return (short)(r >> 16);
}
// packed RNE pair: low16 = bf16(lo), high16 = bf16(hi)
__device__ __forceinline__ unsigned cvtpk(float lo, float hi) {
  unsigned r;
  asm("v_cvt_pk_bf16_f32 %0, %1, %2" : "=v"(r) : "v"(lo), "v"(hi));
  return r;
}
// x = hi + lo, hi = trunc-to-bf16(x) (x-hi exact), lo = RNE(residual)
__device__ __forceinline__ void splitf(float x, short& h, short& l) {
  unsigned u = __builtin_bit_cast(unsigned, x);
  h = (short)(u >> 16);
  float fh = __builtin_bit_cast(float, u & 0xffff0000u);
  l = f2b(x - fh);
}

#define KPLANE 1081600L  // 67600 px * 16 ch

// ---------------------------------------------------------------------------
// Kernel 0: one-time prep — split conv weights hi/lo, convert rel tables,
// zero the 2-px border of all 12 padded K planes (792 KB).
// Grid 108x256 = 27648 threads covers all three tasks.
// ---------------------------------------------------------------------------
__global__ __launch_bounds__(256) void prep_kernel(
    const float* __restrict__ qkv_w, const float* __restrict__ proj_w,
    const float* __restrict__ rel_h, const float* __restrict__ rel_w,
    short* __restrict__ qwh, short* __restrict__ qwl,
    short* __restrict__ pwh, short* __restrict__ pwl,
    short* __restrict__ rhb, short* __restrict__ rwb,
    short* __restrict__ k_t) {
  int i = blockIdx.x * 256 + threadIdx.x;
  if (i < 288 * 96) {
    short h, l;
    splitf(qkv_w[i], h, l);
    qwh[i] = h;
    qwl[i] = l;
  }
  if (i < 96 * 96) {
    short h, l;
    splitf(proj_w[i], h, l);
    pwh[i] = h;
    pwl[i] = l;
  }
  if (i < 368) {
    rhb[i] = f2b(rel_h[i]);
    rwb[i] = f2b(rel_w[i]);
  }
  if (i < 12 * 2064) {  // border pixels: rows {0,1,258,259} + cols {0,1,258,259}
    int plane = i / 2064, r = i - plane * 2064;
    int py, px;
    if (r < 1040) {
      int rowid = r / 260;
      py = (rowid < 2) ? rowid : 256 + rowid;
      px = r - rowid * 260;
    } else {
      int r2 = r - 1040;
      py = 2 + (r2 >> 2);
      int cid = r2 & 3;
      px = (cid < 2) ? cid : 256 + cid;
    }
    bf16x8 z = {0, 0, 0, 0, 0, 0, 0, 0};
    long base = (long)plane * KPLANE + (long)(py * 260 + px) * 16;
    *(bf16x8*)(k_t + base) = z;
    *(bf16x8*)(k_t + base + 8) = z;
  }
}

// ---------------------------------------------------------------------------
// Kernel 1: QKV 1x1 conv.  x RNE-bf16 (single), w hi/lo (exact).  All LDS
// wave-private -> zero barriers.  q/v head-major planes; k padded planes.
// q pre-scaled by 0.25*log2e (exp2 softmax downstream).
// ---------------------------------------------------------------------------
__global__ __launch_bounds__(256) void qkv_kernel(
    const float* __restrict__ x, const short* __restrict__ qwh,
    const short* __restrict__ qwl, const float* __restrict__ bias,
    short* __restrict__ q_t, short* __restrict__ k_t,
    short* __restrict__ v_t) {
  __shared__ __attribute__((aligned(16))) short Ah[4][32][104];
  const int tid = threadIdx.x;
  const int wave = tid >> 6, lane = tid & 63;
  const int quad = lane >> 4, col = lane & 15;
  const long P0 = (long)blockIdx.x * 128 + wave * 32;
  const int b = (int)(P0 >> 16);
  const int hw0 = (int)(P0 & 65535);

  {  // stage: planar f32 -> [pixel][channel] bf16 (RNE), float4 loads
    const long base = ((long)b * 96) << 16;
    const int px0 = (lane & 7) * 4;
    for (int i = 0; i < 12; ++i) {
      int c = i * 8 + (lane >> 3);
      float4 v = *(const float4*)(x + base + ((long)c << 16) + hw0 + px0);
      Ah[wave][px0][c] = f2b(v.x);
      Ah[wave][px0 + 1][c] = f2b(v.y);
      Ah[wave][px0 + 2][c] = f2b(v.z);
      Ah[wave][px0 + 3][c] = f2b(v.w);
    }
  }
  bf16x8 af[2][3];
  for (int mt = 0; mt < 2; ++mt)
    for (int ks = 0; ks < 3; ++ks)
      af[mt][ks] = *(const bf16x8*)&Ah[wave][mt * 16 + col][ks * 32 + quad * 8];

  for (int t = 0; t < 3; ++t) {
    const float scale = (t == 0) ? 0.25f * 1.44269504f : 1.0f;
    for (int i6 = 0; i6 < 6; ++i6) {
      const int o = (t * 6 + i6) * 16 + col;
      bf16x8 bh[3], bl[3];
      for (int ks = 0; ks < 3; ++ks) {
        bh[ks] = *(const bf16x8*)(qwh + o * 96 + ks * 32 + quad * 8);
        bl[ks] = *(const bf16x8*)(qwl + o * 96 + ks * 32 + quad * 8);
      }
      float bv = bias[o];
      f32x4 acc0 = {bv, bv, bv, bv}, acc1 = acc0;
      for (int ks = 0; ks < 3; ++ks) {
        acc0 = mfma16(af[0][ks], bh[ks], acc0);
        acc0 = mfma16(af[0][ks], bl[ks], acc0);
        acc1 = mfma16(af[1][ks], bh[ks], acc1);
        acc1 = mfma16(af[1][ks], bl[ks], acc1);
      }
      for (int r = 0; r < 4; ++r) {
        Ah[wave][quad * 4 + r][i6 * 16 + col] = f2b(acc0[r] * scale);
        Ah[wave][16 + quad * 4 + r][i6 * 16 + col] = f2b(acc1[r] * scale);
      }
    }
    if (t == 1) {  // k: padded planes [head*2+b][260x260][16]
      const int py = (hw0 >> 8) + 2;      // wave-constant (hw0 32-aligned)
      const int pxb = (hw0 & 255) + 2;
      for (int i = 0; i < 6; ++i) {
        int linear = i * 64 + lane;
        int px = linear / 12, c = linear - px * 12;
        int h = c >> 1, half = c & 1;
        bf16x8 vv = *(const bf16x8*)&Ah[wave][px][c * 8];
        *(bf16x8*)(k_t + (long)(h * 2 + b) * KPLANE +
                   (long)(py * 260 + pxb + px) * 16 + half * 8) = vv;
      }
    } else {  // q/v: head-major [head][pix][16]
      short* plane0 = (t == 0) ? q_t : v_t;
      for (int i = 0; i < 6; ++i) {
        int linear = i * 64 + lane;
        int px = linear / 12, c = linear - px * 12;
        int h = c >> 1, half = c & 1;
        bf16x8 vv = *(const bf16x8*)&Ah[wave][px][c * 8];
        *(bf16x8*)(plane0 + (long)h * 2097152 + (P0 + px) * 16 + half * 8) =
            vv;
      }
    }
  }
}

// ---------------------------------------------------------------------------
// Kernel 2: windowed attention.  One block per (window, head); 4 waves = 4
// query tiles; one barrier (V staging).  Padded K planes -> QK loop is
// unconditional b128 loads + constant pointer increments.  Softmax: exp2 on
// pre-scaled logits, denominator via ones-MFMA (row-sum of P on the matrix
// pipe), rcp for the divide.  OOB keys: K=0 stored -> logit=bias; V rows
// zeroed at staging -> numerator 0; exp(bias) enters denominator == ref.
// P path: v_cvt_pk_bf16_f32 packs query pairs -> P^T stored as dwords in
// ppd[key][9] (stride 9 dwords: PV reads hit all 32 banks, parity pairs
// broadcast -> conflict-free).  pa fragments rebuilt with v_perm_b32.
// Keys 144..159 never touch LDS: ks=4 quads 2,3 use register zeros.
// Window index XCD-swizzled (2048 %% 8 == 0 -> bijective) for halo L2 reuse.
// ---------------------------------------------------------------------------
__global__ __launch_bounds__(256) void attn_kernel(
    const short* __restrict__ q_t, const short* __restrict__ k_t,
    const short* __restrict__ v_t, const short* __restrict__ rhb,
    const short* __restrict__ rwb, short* __restrict__ ao) {
  __shared__ __attribute__((aligned(16))) short v_lds[16][168];
  __shared__ __attribute__((aligned(16))) char scratch[4][5248];

  const int orig = blockIdx.x, head = blockIdx.y;
  const int win = ((orig & 7) << 8) | (orig >> 3);  // XCD-chunked swizzle
  const int b = win >> 10, wy = (win & 1023) >> 5, wx = win & 31;
  const int y0 = wy * 8 - 2, x0 = wx * 8 - 2;
  const long pb = (long)b << 16;
  const int tid = threadIdx.x;

  // stage V transposed: v_lds[dh][key]; OOB + pad keys (144..159) zeroed
  if (tid < 160) {
    const int key = tid;
    bool valid = false;
    long pix = 0;
    if (key < 144) {
      int kh = key / 12, kw = key - kh * 12;
      int gy = y0 + kh, gx = x0 + kw;
      valid = ((unsigned)gy < 256u) && ((unsigned)gx < 256u);
      pix = pb + gy * 256 + gx;
    }
    if (valid) {
      const short* src = v_t + (long)head * 2097152 + pix * 16;
      union { bf16x8 v; short s[8]; } u0, u1;
      u0.v = *(const bf16x8*)src;
      u1.v = *(const bf16x8*)(src + 8);
      for (int d = 0; d < 8; ++d) {
        v_lds[d][key] = u0.s[d];
        v_lds[d + 8][key] = u1.s[d];
      }
    } else {
      for (int d = 0; d < 16; ++d) v_lds[d][key] = 0;
    }
  }
  __syncthreads();

  const int wave = tid >> 6, lane = tid & 63;
  const int quad = lane >> 4, col = lane & 15;
  float* dWs = (float*)scratch[wave];  // [30][20] skewed: row r+qx, col ql
  float* dHt = dWs + 600;              // [23][20] transposed
  unsigned* ppd = (unsigned*)scratch[wave];  // [144][9] dwords, reused

  const short* qp = q_t + (long)head * 2097152;
  const short* kpb = k_t + (long)(head * 2 + b) * KPLANE;

  // Q fragment (K padded 16->32: quads 2,3 must be exact zero)
  bf16x8 qf = {0, 0, 0, 0, 0, 0, 0, 0};
  if (quad < 2) {
    int qg = wave * 16 + col;
    int qy = qg >> 3, qx = qg & 7;
    qf = *(const bf16x8*)(qp + (pb + (wy * 8 + qy) * 256 + wx * 8 + qx) * 16 +
                          quad * 8);
  }

  // rel-pos dot tables -> skewed/transposed LDS layouts
  for (int nt = 0; nt < 2; ++nt) {
    int r = nt * 16 + col;
    bf16x8 bw = {0, 0, 0, 0, 0, 0, 0, 0}, bh2 = bw;
    if (quad < 2 && r < 23) {
      bw = *(const bf16x8*)(rwb + r * 16 + quad * 8);
      bh2 = *(const bf16x8*)(rhb + r * 16 + quad * 8);
    }
    f32x4 z = {0.f, 0.f, 0.f, 0.f};
    f32x4 aw = mfma16(qf, bw, z);
    f32x4 ah = mfma16(qf, bh2, z);
    if (r < 23)
      for (int r4 = 0; r4 < 4; ++r4) {
        int ql = quad * 4 + r4;
        dWs[(r + (ql & 7)) * 20 + ql] = aw[r4];
        dHt[r * 20 + ql] = ah[r4];
      }
  }

  // QK^T: 9 key tiles; unconditional loads from padded plane, ptr increments
  f32x4 L[9];
  {
    int kh = (col >= 12) ? 1 : 0, kw = col - 12 * kh;
    const short* ka =
        kpb + (long)((wy * 8 + kh) * 260 + wx * 8 + kw) * 16 + quad * 8;
    for (int nt = 0; nt < 9; ++nt) {
      bf16x8 kf = *(const bf16x8*)ka;  // quads 2,3 read junk * qf=0 -> 0
      f32x4 z = {0.f, 0.f, 0.f, 0.f};
      L[nt] = mfma16(qf, kf, z);
      kw += 4;
      if (kw >= 12) {
        kw -= 12;
        ka += 512 * 16;
      } else {
        ka += 264 * 16;
      }
    }
  }

  // bias + exp2 (logits pre-scaled by log2e via q)
  const int qy4 = wave * 2 + (quad >> 1);
  {
    int kh = (col >= 12) ? 1 : 0, kw = col - 12 * kh;
    for (int nt = 0; nt < 9; ++nt) {
      f32x4 wv = *(const f32x4*)&dWs[(11 + kw) * 20 + quad * 4];
      f32x4 hv = *(const f32x4*)&dHt[(11 + kh - qy4) * 20 + quad * 4];
      for (int r4 = 0; r4 < 4; ++r4)
        L[nt][r4] = __builtin_amdgcn_exp2f(L[nt][r4] + wv[r4] + hv[r4]);
      kw += 4;
      kh += 1;
      if (kw >= 12) {
        kw -= 12;
        kh += 1;
      }
    }
  }
  // fence: dWs/dHt (float) reads above alias ppd (unsigned) writes below;
  // TBAA would otherwise allow reordering across the types.
  asm volatile("" ::: "memory");

  // P^T -> LDS as dwords: ppd[key][qd], qd = query pair (cvt_pk packed)
  for (int nt = 0; nt < 9; ++nt) {
    unsigned d0 = cvtpk(L[nt][0], L[nt][1]);  // queries quad*4+0, +1
    unsigned d1 = cvtpk(L[nt][2], L[nt][3]);  // queries quad*4+2, +3
    int base = (nt * 16 + col) * 9 + quad * 2;
    ppd[base] = d0;
    ppd[base + 1] = d1;
  }

  // P @ V and P @ ones (denominator) — both on the matrix pipe.
  // pa[j] = P[query=col][key=ks*32+quad*8+j] via dword loads + v_perm.
  const unsigned sel = (col & 1) ? 0x07060302u : 0x05040100u;
  const bf16x8 ones = {0x3F80, 0x3F80, 0x3F80, 0x3F80,
                       0x3F80, 0x3F80, 0x3F80, 0x3F80};
  f32x4 oacc = {0.f, 0.f, 0.f, 0.f}, oaccS = oacc;
  for (int ks = 0; ks < 5; ++ks) {
    int k0 = ks * 32 + quad * 8;
    bool live = k0 < 144;            // ks=4, quads 2,3: zero-pad keys
    int k0c = live ? k0 : 136;       // keep LDS reads in-bounds
    const unsigned* rp = ppd + k0c * 9 + (col >> 1);
    unsigned r0 = rp[0], r1 = rp[9], r2 = rp[18], r3 = rp[27];
    unsigned r4v = rp[36], r5 = rp[45], r6 = rp[54], r7 = rp[63];
    union { unsigned u[4]; bf16x8 v; } pu;
    pu.u[0] = live ? __builtin_amdgcn_perm(r1, r0, sel) : 0u;
    pu.u[1] = live ? __builtin_amdgcn_perm(r3, r2, sel) : 0u;
    pu.u[2] = live ? __builtin_amdgcn_perm(r5, r4v, sel) : 0u;
    pu.u[3] = live ? __builtin_amdgcn_perm(r7, r6, sel) : 0u;
    bf16x8 vb = *(const bf16x8*)&v_lds[col][ks * 32 + quad * 8];
    oacc = mfma16(pu.v, vb, oacc);
    oaccS = mfma16(pu.v, ones, oaccS);
  }
  for (int r4 = 0; r4 < 4; ++r4) {
    int qg = wave * 16 + quad * 4 + r4;
    int qy = qg >> 3, qx = qg & 7;
    float val = oacc[r4] * __builtin_amdgcn_rcpf(oaccS[r4]);
    ao[(long)head * 2097152 +
       (pb + (wy * 8 + qy) * 256 + wx * 8 + qx) * 16 + col] = f2b(val);
  }
}

// ---------------------------------------------------------------------------
// Kernel 3: proj 1x1 conv.  C[m=o][n=pixel]; A = pre-split w (hi/lo bf16),
// B = ao (bf16, head-major).  f32 planar output.
// ---------------------------------------------------------------------------
__global__ __launch_bounds__(256) void proj_kernel(
    const short* __restrict__ ao, const short* __restrict__ pwh,
    const short* __restrict__ pwl, const float* __restrict__ bias,
    float* __restrict__ out) {
  const int tid = threadIdx.x;
  const int wave = tid >> 6, lane = tid & 63;
  const int quad = lane >> 4, col = lane & 15;
  const long P0 = (long)blockIdx.x * 128 + wave * 32;

  bf16x8 bfr[2][3];
  for (int nt = 0; nt < 2; ++nt) {
    long pix = P0 + nt * 16 + col;
    for (int ks = 0; ks < 3; ++ks) {
      int c0 = ks * 32 + quad * 8;
      bfr[nt][ks] = *(const bf16x8*)(ao + (long)(c0 >> 4) * 2097152 +
                                     pix * 16 + (c0 & 15));
    }
  }
  f32x4 acc[6][2];
  for (int mt = 0; mt < 6; ++mt) {
    for (int r = 0; r < 4; ++r) {
      float bv = bias[mt * 16 + quad * 4 + r];
      acc[mt][0][r] = bv;
      acc[mt][1][r] = bv;
    }
    bf16x8 afh[3], afl[3];
    for (int ks = 0; ks < 3; ++ks) {
      afh[ks] =
          *(const bf16x8*)(pwh + (mt * 16 + col) * 96 + ks * 32 + quad * 8);
      afl[ks] =
          *(const bf16x8*)(pwl + (mt * 16 + col) * 96 + ks * 32 + quad * 8);
    }
    for (int ks = 0; ks < 3; ++ks) {
      acc[mt][0] = mfma16(afh[ks], bfr[0][ks], acc[mt][0]);
      acc[mt][0] = mfma16(afl[ks], bfr[0][ks], acc[mt][0]);
      acc[mt][1] = mfma16(afh[ks], bfr[1][ks], acc[mt][1]);
      acc[mt][1] = mfma16(afl[ks], bfr[1][ks], acc[mt][1]);
    }
  }
  const int bb = (int)(P0 >> 16);
  const int hw0 = (int)(P0 & 65535);
  for (int mt = 0; mt < 6; ++mt)
    for (int nt = 0; nt < 2; ++nt)
      for (int r = 0; r < 4; ++r) {
        int o = mt * 16 + quad * 4 + r;
        int hw = hw0 + nt * 16 + col;
        out[(((long)(bb * 96 + o)) << 16) + hw] = acc[mt][nt][r];
      }
}

extern "C" void kernel_launch(void* const* d_in, const int* in_sizes, int n_in,
                              void* d_out, int out_size, void* d_ws,
                              size_t ws_size, hipStream_t stream) {
  const float* x = (const float*)d_in[0];
  const float* qkv_w = (const float*)d_in[1];
  const float* qkv_b = (const float*)d_in[2];
  const float* proj_w = (const float*)d_in[3];
  const float* proj_b = (const float*)d_in[4];
  const float* rel_h = (const float*)d_in[5];
  const float* rel_w = (const float*)d_in[6];

  const long NPIXC = 131072L * 96L;
  short* q_t = (short*)d_ws;
  short* k_t = q_t + NPIXC;           // padded: 12 * KPLANE shorts
  short* v_t = k_t + 12 * KPLANE;
  short* ao = v_t + NPIXC;
  short* qwh = ao + NPIXC;
  short* qwl = qwh + 288 * 96;
  short* pwh = qwl + 288 * 96;
  short* pwl = pwh + 96 * 96;
  short* rhb = pwl + 96 * 96;
  short* rwb = rhb + 368;
  float* out = (float*)d_out;

  hipLaunchKernelGGL(prep_kernel, dim3(108), dim3(256), 0, stream, qkv_w,
                     proj_w, rel_h, rel_w, qwh, qwl, pwh, pwl, rhb, rwb, k_t);
  hipLaunchKernelGGL(qkv_kernel, dim3(1024), dim3(256), 0, stream, x, qwh, qwl,
                     qkv_b, q_t, k_t, v_t);
  hipLaunchKernelGGL(attn_kernel, dim3(2048, 6), dim3(256), 0, stream, q_t,
                     k_t, v_t, rhb, rwb, ao);
  hipLaunchKernelGGL(proj_kernel, dim3(1024), dim3(256), 0, stream, ao, pwh,
                     pwl, proj_b, out);
}

// Round 2
// 195.797 us; speedup vs baseline: 1.0803x; 1.0227x over previous
//
#include <hip/hip_runtime.h>
#include <hip/hip_bf16.h>

// HaloNet-style windowed attention, MI355X gfx950.  f32 in / f32 out.
// bf16 MFMA internals; w hi/lo split keeps conv weights exact; x/q/k/v/P/ao
// single bf16 (absmax ~4.9e-4 vs 2.54e-3 threshold).
// ws layout (shorts):
//   q_t [head][pix][16]                    12,582,912   (scaled 0.25*log2e)
//   k_t [head*2+b][260*260 padded][16]     12,979,200   (2-px ZERO border)
//   v_t [head][pix][16]                    12,582,912
//   ao  [head][pix][16]                    12,582,912
//   weights/tables/sbias                       ~75,616
// Total ~101.6 MB.
//
// qkv/proj: LDS-free register GEMMs, operands A=weights / B=pixels so the
// accumulator rows are consecutive OUTPUT CHANNELS of one pixel -> epilogue
// is cvt_pk + dword stores, no LDS repack.  x loaded directly from planar
// f32 (scalar dwords, 4x64B sectors/instr).  Weight fragments prefetched
// one i6 ahead; wave owns 64 px so the weight panel is read once per 64 px.

typedef __attribute__((ext_vector_type(8))) short bf16x8;
typedef __attribute__((ext_vector_type(4))) float f32x4;

__device__ __forceinline__ f32x4 mfma16(bf16x8 a, bf16x8 b, f32x4 c) {
  // C/D: col=lane&15 (B-idx), row=(lane>>4)*4+reg (A-idx)
  // A/B frag: idx=lane&15, k=(lane>>4)*8+j   [learn_hip m89/m91]
  return __builtin_amdgcn_mfma_f32_16x16x32_bf16(a, b, c, 0, 0, 0);
}
// branchless RNE f32->bf16 (finite inputs only — true for this problem)
__device__ __forceinline__ short f2b(float f) {
  unsigned u = __builtin_bit_cast(unsigned, f);
  unsigned r = u + 0x7fffu + ((u >> 16) & 1u);
  return (short)(r >> 16);
}
// packed RNE pair: low16 = bf16(lo), high16 = bf16(hi)
__device__ __forceinline__ unsigned cvtpk(float lo, float hi) {
  unsigned r;
  asm("v_cvt_pk_bf16_f32 %0, %1, %2" : "=v"(r) : "v"(lo), "v"(hi));
  return r;
}
// x = hi + lo, hi = trunc-to-bf16(x) (x-hi exact), lo = RNE(residual)
__device__ __forceinline__ void splitf(float x, short& h, short& l) {
  unsigned u = __builtin_bit_cast(unsigned, x);
  h = (short)(u >> 16);
  float fh = __builtin_bit_cast(float, u & 0xffff0000u);
  l = f2b(x - fh);
}

#define KPLANE 1081600L  // 67600 px * 16 ch
#define QS (0.25f * 1.44269504f)

// ---------------------------------------------------------------------------
// Kernel 0: one-time prep — split conv weights hi/lo (q rows pre-scaled by
// 0.25*log2e), scaled bias, rel tables, zero the 2-px border of all 12
// padded K planes.  Grid 108x256 = 27648 threads covers all tasks.
// ---------------------------------------------------------------------------
__global__ __launch_bounds__(256) void prep_kernel(
    const float* __restrict__ qkv_w, const float* __restrict__ proj_w,
    const float* __restrict__ rel_h, const float* __restrict__ rel_w,
    const float* __restrict__ qkv_b,
    short* __restrict__ qwh, short* __restrict__ qwl,
    short* __restrict__ pwh, short* __restrict__ pwl,
    short* __restrict__ rhb, short* __restrict__ rwb,
    float* __restrict__ sbias, short* __restrict__ k_t) {
  int i = blockIdx.x * 256 + threadIdx.x;
  if (i < 288 * 96) {
    float wv = qkv_w[i];
    if (i < 96 * 96) wv *= QS;  // q rows pre-scaled
    short h, l;
    splitf(wv, h, l);
    qwh[i] = h;
    qwl[i] = l;
  }
  if (i < 96 * 96) {
    short h, l;
    splitf(proj_w[i], h, l);
    pwh[i] = h;
    pwl[i] = l;
  }
  if (i < 368) {
    rhb[i] = f2b(rel_h[i]);
    rwb[i] = f2b(rel_w[i]);
  }
  if (i < 288) sbias[i] = qkv_b[i] * (i < 96 ? QS : 1.0f);
  if (i < 12 * 2064) {  // border pixels: rows {0,1,258,259} + cols {0,1,258,259}
    int plane = i / 2064, r = i - plane * 2064;
    int py, px;
    if (r < 1040) {
      int rowid = r / 260;
      py = (rowid < 2) ? rowid : 256 + rowid;
      px = r - rowid * 260;
    } else {
      int r2 = r - 1040;
      py = 2 + (r2 >> 2);
      int cid = r2 & 3;
      px = (cid < 2) ? cid : 256 + cid;
    }
    bf16x8 z = {0, 0, 0, 0, 0, 0, 0, 0};
    long base = (long)plane * KPLANE + (long)(py * 260 + px) * 16;
    *(bf16x8*)(k_t + base) = z;
    *(bf16x8*)(k_t + base + 8) = z;
  }
}

// ---------------------------------------------------------------------------
// Kernel 1: QKV 1x1 conv.  LDS-free.  512 blocks x 4 waves; wave = 64 px
// (one quarter of an image row).  B-frag (pixels) direct from planar f32:
// lane reads x[ks*32+quad*8+j][px0+col] (8 scalar dwords -> cvt_pk pack).
// A = pre-split weights, prefetched one i6 ahead.  C row = output channel,
// col = pixel -> epilogue: 2 cvt_pk + 2 dword stores per tile.
// ---------------------------------------------------------------------------
__global__ __launch_bounds__(256) void qkv_kernel(
    const float* __restrict__ x, const short* __restrict__ qwh,
    const short* __restrict__ qwl, const float* __restrict__ sbias,
    short* __restrict__ q_t, short* __restrict__ k_t,
    short* __restrict__ v_t) {
  const int tid = threadIdx.x;
  const int wave = tid >> 6, lane = tid & 63;
  const int quad = lane >> 4, col = lane & 15;
  const int blk = blockIdx.x;        // 512 blocks = 2 images x 256 rows
  const int b = blk >> 8, row = blk & 255;

  // ---- B fragments: x[ch][pix] -> bf16, pixel=col, k=quad*8+j
  const float* xw = x + (((long)b * 96) << 16) + row * 256 + wave * 64 + col;
  bf16x8 bx[4][3];
#pragma unroll
  for (int tile = 0; tile < 4; ++tile)
#pragma unroll
    for (int ks = 0; ks < 3; ++ks) {
      const float* p = xw + tile * 16 + (((long)(ks * 32 + quad * 8)) << 16);
      float v0 = p[0];
      float v1 = p[1L << 16];
      float v2 = p[2L << 16];
      float v3 = p[3L << 16];
      float v4 = p[4L << 16];
      float v5 = p[5L << 16];
      float v6 = p[6L << 16];
      float v7 = p[7L << 16];
      union { unsigned u[4]; bf16x8 w; } t;
      t.u[0] = cvtpk(v0, v1);
      t.u[1] = cvtpk(v2, v3);
      t.u[2] = cvtpk(v4, v5);
      t.u[3] = cvtpk(v6, v7);
      bx[tile][ks] = t.w;
    }

  // ---- weight fragments (A): row = output = base+col
  const short* wbh = qwh + col * 96 + quad * 8;
  const short* wbl = qwl + col * 96 + quad * 8;
  bf16x8 wh[3], wl[3];
#pragma unroll
  for (int ks = 0; ks < 3; ++ks) {
    wh[ks] = *(const bf16x8*)(wbh + ks * 32);
    wl[ks] = *(const bf16x8*)(wbl + ks * 32);
  }

  const long pixb = (long)blk * 256 + wave * 64 + col;  // tile0 pixel
  short* kbase = k_t + (long)b * KPLANE +
                 ((long)((row + 2) * 260 + wave * 64 + col + 2)) * 16 +
                 quad * 4;

#pragma unroll
  for (int t6 = 0; t6 < 18; ++t6) {
    bf16x8 nh[3], nl[3];
    if (t6 < 17) {
#pragma unroll
      for (int ks = 0; ks < 3; ++ks) {
        nh[ks] = *(const bf16x8*)(wbh + (t6 + 1) * 1536 + ks * 32);
        nl[ks] = *(const bf16x8*)(wbl + (t6 + 1) * 1536 + ks * 32);
      }
    }
    f32x4 bv = *(const f32x4*)(sbias + t6 * 16 + quad * 4);
    f32x4 acc[4] = {bv, bv, bv, bv};
#pragma unroll
    for (int ks = 0; ks < 3; ++ks)
#pragma unroll
      for (int tile = 0; tile < 4; ++tile) {
        acc[tile] = mfma16(wh[ks], bx[tile][ks], acc[tile]);
        acc[tile] = mfma16(wl[ks], bx[tile][ks], acc[tile]);
      }
#pragma unroll
    for (int tile = 0; tile < 4; ++tile) {
      unsigned d0 = cvtpk(acc[tile][0], acc[tile][1]);  // ch quad*4+0,1
      unsigned d1 = cvtpk(acc[tile][2], acc[tile][3]);  // ch quad*4+2,3
      if (t6 >= 6 && t6 < 12) {  // k: padded planes [head*2+b]
        short* kp = kbase + (long)(t6 - 6) * (2 * KPLANE) + tile * 256;
        *(unsigned*)kp = d0;
        *(unsigned*)(kp + 2) = d1;
      } else {  // q/v: head-major [head][pix][16]
        short* plane = (t6 < 6 ? q_t : v_t) +
                       (long)(t6 < 6 ? t6 : t6 - 12) * 2097152 + pixb * 16 +
                       tile * 256 + quad * 4;
        *(unsigned*)plane = d0;
        *(unsigned*)(plane + 2) = d1;
      }
    }
    if (t6 < 17) {
#pragma unroll
      for (int ks = 0; ks < 3; ++ks) {
        wh[ks] = nh[ks];
        wl[ks] = nl[ks];
      }
    }
  }
}

// ---------------------------------------------------------------------------
// Kernel 2: windowed attention (unchanged from prior round).
// ---------------------------------------------------------------------------
__global__ __launch_bounds__(256) void attn_kernel(
    const short* __restrict__ q_t, const short* __restrict__ k_t,
    const short* __restrict__ v_t, const short* __restrict__ rhb,
    const short* __restrict__ rwb, short* __restrict__ ao) {
  __shared__ __attribute__((aligned(16))) short v_lds[16][168];
  __shared__ __attribute__((aligned(16))) char scratch[4][5248];

  const int orig = blockIdx.x, head = blockIdx.y;
  const int win = ((orig & 7) << 8) | (orig >> 3);  // XCD-chunked swizzle
  const int b = win >> 10, wy = (win & 1023) >> 5, wx = win & 31;
  const int y0 = wy * 8 - 2, x0 = wx * 8 - 2;
  const long pb = (long)b << 16;
  const int tid = threadIdx.x;

  // stage V transposed: v_lds[dh][key]; OOB + pad keys (144..159) zeroed
  if (tid < 160) {
    const int key = tid;
    bool valid = false;
    long pix = 0;
    if (key < 144) {
      int kh = key / 12, kw = key - kh * 12;
      int gy = y0 + kh, gx = x0 + kw;
      valid = ((unsigned)gy < 256u) && ((unsigned)gx < 256u);
      pix = pb + gy * 256 + gx;
    }
    if (valid) {
      const short* src = v_t + (long)head * 2097152 + pix * 16;
      union { bf16x8 v; short s[8]; } u0, u1;
      u0.v = *(const bf16x8*)src;
      u1.v = *(const bf16x8*)(src + 8);
      for (int d = 0; d < 8; ++d) {
        v_lds[d][key] = u0.s[d];
        v_lds[d + 8][key] = u1.s[d];
      }
    } else {
      for (int d = 0; d < 16; ++d) v_lds[d][key] = 0;
    }
  }
  __syncthreads();

  const int wave = tid >> 6, lane = tid & 63;
  const int quad = lane >> 4, col = lane & 15;
  float* dWs = (float*)scratch[wave];  // [30][20] skewed: row r+qx, col ql
  float* dHt = dWs + 600;              // [23][20] transposed
  unsigned* ppd = (unsigned*)scratch[wave];  // [144][9] dwords, reused

  const short* qp = q_t + (long)head * 2097152;
  const short* kpb = k_t + (long)(head * 2 + b) * KPLANE;

  // Q fragment (K padded 16->32: quads 2,3 must be exact zero)
  bf16x8 qf = {0, 0, 0, 0, 0, 0, 0, 0};
  if (quad < 2) {
    int qg = wave * 16 + col;
    int qy = qg >> 3, qx = qg & 7;
    qf = *(const bf16x8*)(qp + (pb + (wy * 8 + qy) * 256 + wx * 8 + qx) * 16 +
                          quad * 8);
  }

  // rel-pos dot tables -> skewed/transposed LDS layouts
  for (int nt = 0; nt < 2; ++nt) {
    int r = nt * 16 + col;
    bf16x8 bw = {0, 0, 0, 0, 0, 0, 0, 0}, bh2 = bw;
    if (quad < 2 && r < 23) {
      bw = *(const bf16x8*)(rwb + r * 16 + quad * 8);
      bh2 = *(const bf16x8*)(rhb + r * 16 + quad * 8);
    }
    f32x4 z = {0.f, 0.f, 0.f, 0.f};
    f32x4 aw = mfma16(qf, bw, z);
    f32x4 ah = mfma16(qf, bh2, z);
    if (r < 23)
      for (int r4 = 0; r4 < 4; ++r4) {
        int ql = quad * 4 + r4;
        dWs[(r + (ql & 7)) * 20 + ql] = aw[r4];
        dHt[r * 20 + ql] = ah[r4];
      }
  }

  // QK^T: 9 key tiles; unconditional loads from padded plane, ptr increments
  f32x4 L[9];
  {
    int kh = (col >= 12) ? 1 : 0, kw = col - 12 * kh;
    const short* ka =
        kpb + (long)((wy * 8 + kh) * 260 + wx * 8 + kw) * 16 + quad * 8;
    for (int nt = 0; nt < 9; ++nt) {
      bf16x8 kf = *(const bf16x8*)ka;  // quads 2,3 read junk * qf=0 -> 0
      f32x4 z = {0.f, 0.f, 0.f, 0.f};
      L[nt] = mfma16(qf, kf, z);
      kw += 4;
      if (kw >= 12) {
        kw -= 12;
        ka += 512 * 16;
      } else {
        ka += 264 * 16;
      }
    }
  }

  // bias + exp2 (logits pre-scaled by log2e via q)
  const int qy4 = wave * 2 + (quad >> 1);
  {
    int kh = (col >= 12) ? 1 : 0, kw = col - 12 * kh;
    for (int nt = 0; nt < 9; ++nt) {
      f32x4 wv = *(const f32x4*)&dWs[(11 + kw) * 20 + quad * 4];
      f32x4 hv = *(const f32x4*)&dHt[(11 + kh - qy4) * 20 + quad * 4];
      for (int r4 = 0; r4 < 4; ++r4)
        L[nt][r4] = __builtin_amdgcn_exp2f(L[nt][r4] + wv[r4] + hv[r4]);
      kw += 4;
      kh += 1;
      if (kw >= 12) {
        kw -= 12;
        kh += 1;
      }
    }
  }
  // fence: dWs/dHt (float) reads above alias ppd (unsigned) writes below;
  // TBAA would otherwise allow reordering across the types.
  asm volatile("" ::: "memory");

  // P^T -> LDS as dwords: ppd[key][qd], qd = query pair (cvt_pk packed)
  for (int nt = 0; nt < 9; ++nt) {
    unsigned d0 = cvtpk(L[nt][0], L[nt][1]);  // queries quad*4+0, +1
    unsigned d1 = cvtpk(L[nt][2], L[nt][3]);  // queries quad*4+2, +3
    int base = (nt * 16 + col) * 9 + quad * 2;
    ppd[base] = d0;
    ppd[base + 1] = d1;
  }

  // P @ V and P @ ones (denominator) — both on the matrix pipe.
  // pa[j] = P[query=col][key=ks*32+quad*8+j] via dword loads + v_perm.
  const unsigned sel = (col & 1) ? 0x07060302u : 0x05040100u;
  const bf16x8 ones = {0x3F80, 0x3F80, 0x3F80, 0x3F80,
                       0x3F80, 0x3F80, 0x3F80, 0x3F80};
  f32x4 oacc = {0.f, 0.f, 0.f, 0.f}, oaccS = oacc;
  for (int ks = 0; ks < 5; ++ks) {
    int k0 = ks * 32 + quad * 8;
    bool live = k0 < 144;            // ks=4, quads 2,3: zero-pad keys
    int k0c = live ? k0 : 136;       // keep LDS reads in-bounds
    const unsigned* rp = ppd + k0c * 9 + (col >> 1);
    unsigned r0 = rp[0], r1 = rp[9], r2 = rp[18], r3 = rp[27];
    unsigned r4v = rp[36], r5 = rp[45], r6 = rp[54], r7 = rp[63];
    union { unsigned u[4]; bf16x8 v; } pu;
    pu.u[0] = live ? __builtin_amdgcn_perm(r1, r0, sel) : 0u;
    pu.u[1] = live ? __builtin_amdgcn_perm(r3, r2, sel) : 0u;
    pu.u[2] = live ? __builtin_amdgcn_perm(r5, r4v, sel) : 0u;
    pu.u[3] = live ? __builtin_amdgcn_perm(r7, r6, sel) : 0u;
    bf16x8 vb = *(const bf16x8*)&v_lds[col][ks * 32 + quad * 8];
    oacc = mfma16(pu.v, vb, oacc);
    oaccS = mfma16(pu.v, ones, oaccS);
  }
  for (int r4 = 0; r4 < 4; ++r4) {
    int qg = wave * 16 + quad * 4 + r4;
    int qy = qg >> 3, qx = qg & 7;
    float val = oacc[r4] * __builtin_amdgcn_rcpf(oaccS[r4]);
    ao[(long)head * 2097152 +
       (pb + (wy * 8 + qy) * 256 + wx * 8 + qx) * 16 + col] = f2b(val);
  }
}

// ---------------------------------------------------------------------------
// Kernel 3: proj 1x1 conv.  LDS-free, same structure as qkv: A = pre-split
// weights (prefetched), B = ao pixels (b128 loads from head-major planes),
// C row = output channel -> scalar f32 planar stores (4x64B sectors/instr).
// ---------------------------------------------------------------------------
__global__ __launch_bounds__(256) void proj_kernel(
    const short* __restrict__ ao, const short* __restrict__ pwh,
    const short* __restrict__ pwl, const float* __restrict__ bias,
    float* __restrict__ out) {
  const int tid = threadIdx.x;
  const int wave = tid >> 6, lane = tid & 63;
  const int quad = lane >> 4, col = lane & 15;
  const int blk = blockIdx.x;  // 512 blocks
  const int b = blk >> 8;
  const long pix0 = (long)blk * 256 + wave * 64 + col;

  bf16x8 bfr[4][3];
#pragma unroll
  for (int tile = 0; tile < 4; ++tile)
#pragma unroll
    for (int ks = 0; ks < 3; ++ks) {
      int head = 2 * ks + (quad >> 1);
      bfr[tile][ks] =
          *(const bf16x8*)(ao + (long)head * 2097152 +
                           (pix0 + tile * 16) * 16 + (quad & 1) * 8);
    }

  const short* wbh = pwh + col * 96 + quad * 8;
  const short* wbl = pwl + col * 96 + quad * 8;
  bf16x8 ah[3], al[3];
#pragma unroll
  for (int ks = 0; ks < 3; ++ks) {
    ah[ks] = *(const bf16x8*)(wbh + ks * 32);
    al[ks] = *(const bf16x8*)(wbl + ks * 32);
  }
  float* ob = out + (((long)(b * 96 + quad * 4)) << 16) + (blk & 255) * 256 +
              wave * 64 + col;
#pragma unroll
  for (int mt = 0; mt < 6; ++mt) {
    bf16x8 nh[3], nl[3];
    if (mt < 5) {
#pragma unroll
      for (int ks = 0; ks < 3; ++ks) {
        nh[ks] = *(const bf16x8*)(wbh + (mt + 1) * 1536 + ks * 32);
        nl[ks] = *(const bf16x8*)(wbl + (mt + 1) * 1536 + ks * 32);
      }
    }
    f32x4 bv = *(const f32x4*)(bias + mt * 16 + quad * 4);
    f32x4 acc[4] = {bv, bv, bv, bv};
#pragma unroll
    for (int ks = 0; ks < 3; ++ks)
#pragma unroll
      for (int tile = 0; tile < 4; ++tile) {
        acc[tile] = mfma16(ah[ks], bfr[tile][ks], acc[tile]);
        acc[tile] = mfma16(al[ks], bfr[tile][ks], acc[tile]);
      }
    float* obm = ob + ((long)(mt * 16) << 16);
#pragma unroll
    for (int tile = 0; tile < 4; ++tile)
#pragma unroll
      for (int r = 0; r < 4; ++r)
        obm[((long)r << 16) + tile * 16] = acc[tile][r];
    if (mt < 5) {
#pragma unroll
      for (int ks = 0; ks < 3; ++ks) {
        ah[ks] = nh[ks];
        al[ks] = nl[ks];
      }
    }
  }
}

extern "C" void kernel_launch(void* const* d_in, const int* in_sizes, int n_in,
                              void* d_out, int out_size, void* d_ws,
                              size_t ws_size, hipStream_t stream) {
  const float* x = (const float*)d_in[0];
  const float* qkv_w = (const float*)d_in[1];
  const float* qkv_b = (const float*)d_in[2];
  const float* proj_w = (const float*)d_in[3];
  const float* proj_b = (const float*)d_in[4];
  const float* rel_h = (const float*)d_in[5];
  const float* rel_w = (const float*)d_in[6];

  const long NPIXC = 131072L * 96L;
  short* q_t = (short*)d_ws;
  short* k_t = q_t + NPIXC;           // padded: 12 * KPLANE shorts
  short* v_t = k_t + 12 * KPLANE;
  short* ao = v_t + NPIXC;
  short* qwh = ao + NPIXC;
  short* qwl = qwh + 288 * 96;
  short* pwh = qwl + 288 * 96;
  short* pwl = pwh + 96 * 96;
  short* rhb = pwl + 96 * 96;
  short* rwb = rhb + 368;
  float* sbias = (float*)(rwb + 368);
  float* out = (float*)d_out;

  hipLaunchKernelGGL(prep_kernel, dim3(108), dim3(256), 0, stream, qkv_w,
                     proj_w, rel_h, rel_w, qkv_b, qwh, qwl, pwh, pwl, rhb, rwb,
                     sbias, k_t);
  hipLaunchKernelGGL(qkv_kernel, dim3(512), dim3(256), 0, stream, x, qwh, qwl,
                     sbias, q_t, k_t, v_t);
  hipLaunchKernelGGL(attn_kernel, dim3(2048, 6), dim3(256), 0, stream, q_t,
                     k_t, v_t, rhb, rwb, ao);
  hipLaunchKernelGGL(proj_kernel, dim3(512), dim3(256), 0, stream, ao, pwh,
                     pwl, proj_b, out);
}